// Round 7
// baseline (419.409 us; speedup 1.0000x reference)
//
#include <hip/hip_runtime.h>
#include <math.h>

typedef _Float16 f16;
typedef f16 f16x2 __attribute__((ext_vector_type(2)));
typedef f16 f16x4 __attribute__((ext_vector_type(4)));
typedef f16 f16x8 __attribute__((ext_vector_type(8)));
typedef float f32x4 __attribute__((ext_vector_type(4)));

// ---- shared MFMA helpers: 128x128x128 f16 matmul from XOR-swizzled LDS ----
__device__ __forceinline__ void stage_pair(const f16* __restrict__ L,
                                           const f16* __restrict__ Rt,
                                           f16* sL, f16* sRt, int t) {
#pragma unroll
  for (int j = 0; j < 8; ++j) {
    const int ck = j * 256 + t, row = ck >> 4, c16 = ck & 15;
    const int off = ((row << 8) + (c16 << 4)) ^ ((row & 7) << 4);
    *(f16x8*)((char*)sL + off) = *(const f16x8*)(L + ck * 8);
    *(f16x8*)((char*)sRt + off) = *(const f16x8*)(Rt + ck * 8);
  }
}

__device__ __forceinline__ void mm128(const f16* sL, const f16* sRt,
                                      f32x4 acc[2][8], int w, int lr, int lg) {
#pragma unroll
  for (int kt = 0; kt < 4; ++kt) {
    int row = w * 32 + lr;
    int byt = ((row << 8) + kt * 64 + (lg << 4)) ^ ((row & 7) << 4);
    const f16x8 a0 = *(const f16x8*)((const char*)sL + byt);
    row += 16;
    byt = ((row << 8) + kt * 64 + (lg << 4)) ^ ((row & 7) << 4);
    const f16x8 a1 = *(const f16x8*)((const char*)sL + byt);
#pragma unroll
    for (int nt = 0; nt < 8; ++nt) {
      const int rb = nt * 16 + lr;
      const int bb = ((rb << 8) + kt * 64 + (lg << 4)) ^ ((rb & 7) << 4);
      const f16x8 bv = *(const f16x8*)((const char*)sRt + bb);
      acc[0][nt] = __builtin_amdgcn_mfma_f32_16x16x32_f16(a0, bv, acc[0][nt], 0, 0, 0);
      acc[1][nt] = __builtin_amdgcn_mfma_f32_16x16x32_f16(a1, bv, acc[1][nt], 0, 0, 0);
    }
  }
}

// ---- repack: w2 -> f16 hi/lo [h/l][tap][oc][ic]; w1 -> w1p[oc][k32]; lw -> lwT
__global__ __launch_bounds__(256) void k_repack(const float* __restrict__ w2,
                                                const float* __restrict__ w1,
                                                const float* __restrict__ lw,
                                                f16* __restrict__ w2p,
                                                f16* __restrict__ w1p,
                                                float* __restrict__ lwT,
                                                float* __restrict__ lossAcc) {
  const int i = blockIdx.x * 256 + threadIdx.x;
  if (i == 0) lossAcc[0] = 0.f;
  if (i < 18432) {
    const int ic = i & 31, oc = (i >> 5) & 63, tap = i >> 11;
    const float w = w2[oc * 288 + ic * 9 + tap];
    const f16 wh = (f16)w;
    w2p[i] = wh;
    w2p[18432 + i] = (f16)(w - (float)wh);
  }
  if (i < 1024) {
    const int oc = i >> 5, k = i & 31;
    f16 r = (f16)0.f;
    if (k < 9) r = (f16)w1[oc * 9 + k];
    else if (k >= 16 && k < 25) {
      const float w = w1[oc * 9 + (k - 16)];
      r = (f16)(w - (float)((f16)w));
    }
    w1p[i] = r;
  }
  if (i < 8192) lwT[i] = lw[(i & 63) * 128 + (i >> 6)];  // lwT[o][c]
}

// ---- fused encoder (LDS 23.4KB -> 6 blocks/CU)
__global__ __launch_bounds__(256, 6) void k_encoder(
    const float* __restrict__ seq,
    const f16* __restrict__ w1p, const float* __restrict__ b1,
    const f16* __restrict__ w2p, const float* __restrict__ b2,
    const float* __restrict__ lwT, const float* __restrict__ lb,
    f16* __restrict__ emb16)
{
  __shared__ __align__(16) f16 s_in16[33 * 34];   // [iy][ix] stride 34
  __shared__ __align__(16) f16 s_h1[289 * 36];    // row = iy*17+ix, stride 36 f16
  __shared__ __align__(16) float s_pool[64];
  __shared__ float s_part[2];
  const int t = threadIdx.x, lane = t & 63, wv = t >> 6;
  const int lr = lane & 15, lg = lane >> 4;

  // stage input as f16 (float4 load, two f16x2 stores)
  {
    const float* x = seq + (size_t)blockIdx.x * 1024;
    const f32x4 v4 = *(const f32x4*)(x + t * 4);
    const int row = t >> 3, col = (t & 7) * 4;
    *(f16x2*)&s_in16[row * 34 + col] = f16x2{(f16)v4[0], (f16)v4[1]};
    *(f16x2*)&s_in16[row * 34 + col + 2] = f16x2{(f16)v4[2], (f16)v4[3]};
  }
  if (t < 32) { s_in16[t * 34 + 32] = (f16)0.f; s_in16[t * 34 + 33] = (f16)0.f; }
  if (t < 34) s_in16[32 * 34 + t] = (f16)0.f;
  // zero h1 pad rows (ix==16: rows 16+17*zi; iy==16: rows 272..288): 33 rows x 32 f16
  for (int zi = t; zi < 264; zi += 256) {
    const int rr = zi >> 3, ch = zi & 7;
    const int row = (rr < 16) ? rr * 17 + 16 : 272 + (rr - 16);
    *(f16x4*)&s_h1[row * 36 + ch * 4] = f16x4{(f16)0.f, (f16)0.f, (f16)0.f, (f16)0.f};
  }
  // conv1 B fragments + biases
  f16x8 w1f[2];
  float b1v[2];
#pragma unroll
  for (int n = 0; n < 2; ++n) {
    w1f[n] = *(const f16x8*)(w1p + (n * 16 + lr) * 32 + lg * 8);
    b1v[n] = b1[n * 16 + lr];
  }
  __syncthreads();

  // conv1 via MFMA: m-tile = output row oy, M=16 ox, N=2x16 oc, K=32 (hi|lo taps)
  {
    const bool odd = lg & 1;
    f32x4 a1[4][2];
#pragma unroll
    for (int m = 0; m < 4; ++m) {
      const int oy = wv * 4 + m;
      const int base = 68 * oy + 2 * lr;
      f16x8 af;
      if (odd) {
        af = f16x8{s_in16[base + 70], (f16)0.f, (f16)0.f, (f16)0.f,
                   (f16)0.f, (f16)0.f, (f16)0.f, (f16)0.f};
      } else {
        af[0] = s_in16[base];      af[1] = s_in16[base + 1];  af[2] = s_in16[base + 2];
        af[3] = s_in16[base + 34]; af[4] = s_in16[base + 35]; af[5] = s_in16[base + 36];
        af[6] = s_in16[base + 68]; af[7] = s_in16[base + 69];
      }
#pragma unroll
      for (int n = 0; n < 2; ++n) {
        const f32x4 c0 = f32x4{b1v[n], b1v[n], b1v[n], b1v[n]};
        a1[m][n] = __builtin_amdgcn_mfma_f32_16x16x32_f16(af, w1f[n], c0, 0, 0, 0);
      }
    }
#pragma unroll
    for (int m = 0; m < 4; ++m) {
      const int oy = wv * 4 + m;
#pragma unroll
      for (int n = 0; n < 2; ++n)
#pragma unroll
        for (int v = 0; v < 4; ++v)
          s_h1[(oy * 17 + lg * 4 + v) * 36 + n * 16 + lr] = (f16)fmaxf(a1[m][n][v], 0.f);
    }
  }
  // conv2 B-fragments (hi/lo)
  f16x8 bh[9], bl[9];
  float bias2;
  {
    const int oc = wv * 16 + lr;
#pragma unroll
    for (int tap = 0; tap < 9; ++tap) {
      bh[tap] = *(const f16x8*)(w2p + ((tap * 64 + oc) * 32 + lg * 8));
      bl[tap] = *(const f16x8*)(w2p + 18432 + ((tap * 64 + oc) * 32 + lg * 8));
    }
    bias2 = b2[oc];
  }
  __syncthreads();

  // conv2 MFMA: M=64 pos (4 tiles), N=16 oc (this wave), K=32 ic per tap
  {
    f32x4 acc[4];
#pragma unroll
    for (int m = 0; m < 4; ++m) acc[m] = f32x4{bias2, bias2, bias2, bias2};
#pragma unroll
    for (int m = 0; m < 4; ++m) {
      const int opos = m * 16 + lr, oy = opos >> 3, ox = opos & 7;
      const int baddr = (34 * oy + 2 * ox) * 36 + lg * 8;
#pragma unroll
      for (int dy = 0; dy < 3; ++dy)
#pragma unroll
        for (int dx = 0; dx < 3; ++dx) {
          const int tap = dy * 3 + dx;
          const f16x8 afr = *(const f16x8*)&s_h1[baddr + (dy * 17 + dx) * 36];
          acc[m] = __builtin_amdgcn_mfma_f32_16x16x32_f16(afr, bh[tap], acc[m], 0, 0, 0);
          acc[m] = __builtin_amdgcn_mfma_f32_16x16x32_f16(afr, bl[tap], acc[m], 0, 0, 0);
        }
    }
    float s = 0.f;
#pragma unroll
    for (int m = 0; m < 4; ++m)
#pragma unroll
      for (int v = 0; v < 4; ++v) s += fmaxf(acc[m][v], 0.f);
    s += __shfl_xor(s, 16, 64);
    s += __shfl_xor(s, 32, 64);
    if (lane < 16) s_pool[wv * 16 + lane] = s * (1.f / 64.f);
  }
  __syncthreads();
  // linear 64->128 + L2 normalize, f16 out
  float val = 0.f;
  if (t < 128) {
    val = lb[t];
    const float* lrow = lwT + t * 64;
#pragma unroll
    for (int c4 = 0; c4 < 16; ++c4) {
      const f32x4 wv4 = *(const f32x4*)(lrow + c4 * 4);
      const f32x4 pv = *(const f32x4*)&s_pool[c4 * 4];
      val = fmaf(pv[0], wv4[0], val);
      val = fmaf(pv[1], wv4[1], val);
      val = fmaf(pv[2], wv4[2], val);
      val = fmaf(pv[3], wv4[3], val);
    }
  }
  float sq = val * val;
#pragma unroll
  for (int off = 1; off < 64; off <<= 1) sq += __shfl_xor(sq, off, 64);
  if (t < 128 && (t & 63) == 0) s_part[t >> 6] = sq;
  __syncthreads();
  if (t < 128) {
    const float nrm = sqrtf(s_part[0] + s_part[1]);
    emb16[(size_t)blockIdx.x * 128 + t] = (f16)(val / fmaxf(nrm, 1e-12f));
  }
}

// ---- fused affinity + dual softmax; stores row+T forms of both S matrices; At_1 loss at tt==0
__global__ __launch_bounds__(256) void k_affsm(
    const f16* __restrict__ emb16, float* __restrict__ Aout,
    f16* __restrict__ Srow, f16* __restrict__ ST, float* __restrict__ loss)
{
  __shared__ __align__(16) f16 sL[16384];
  __shared__ __align__(16) f16 sR[16384];
  __shared__ __align__(16) f16 sT[128 * 136];
  __shared__ float s_cm[128], s_cd[128];
  __shared__ float s_red4[512];
  __shared__ float s_lred[4];
  const int bid = blockIdx.x, b = bid / 9, tt = bid % 9;
  const int t = threadIdx.x, lane = t & 63, w = t >> 6;
  const int lr = lane & 15, lg = lane >> 4;
  const f16* Ea = emb16 + (size_t)(b * 10 + tt) * 16384;
  stage_pair(Ea, Ea + 16384, sL, sR, t);
  __syncthreads();
  f32x4 acc[2][8] = {};
  mm128(sL, sR, acc, w, lr, lg);
#pragma unroll
  for (int mt = 0; mt < 2; ++mt)
#pragma unroll
    for (int nt = 0; nt < 8; ++nt)
#pragma unroll
      for (int v = 0; v < 4; ++v) acc[mt][nt][v] *= (1.f / 0.07f);

  // write A
  float* Og = Aout + (size_t)bid * 16384;
#pragma unroll
  for (int mt = 0; mt < 2; ++mt)
#pragma unroll
    for (int nt = 0; nt < 8; ++nt)
#pragma unroll
      for (int v = 0; v < 4; ++v)
        Og[(w * 32 + mt * 16 + lg * 4 + v) * 128 + nt * 16 + lr] = acc[mt][nt][v];

  if (tt == 8) return;

  // row stats
  float rm[2][4], rd[2][4];
#pragma unroll
  for (int mt = 0; mt < 2; ++mt)
#pragma unroll
    for (int v = 0; v < 4; ++v) {
      float m = -1e30f;
#pragma unroll
      for (int nt = 0; nt < 8; ++nt) m = fmaxf(m, acc[mt][nt][v]);
      m = fmaxf(m, __shfl_xor(m, 1, 64));
      m = fmaxf(m, __shfl_xor(m, 2, 64));
      m = fmaxf(m, __shfl_xor(m, 4, 64));
      m = fmaxf(m, __shfl_xor(m, 8, 64));
      float s = 0.f;
#pragma unroll
      for (int nt = 0; nt < 8; ++nt) s += expf(acc[mt][nt][v] - m);
      s += __shfl_xor(s, 1, 64);
      s += __shfl_xor(s, 2, 64);
      s += __shfl_xor(s, 4, 64);
      s += __shfl_xor(s, 8, 64);
      rm[mt][v] = m;
      rd[mt][v] = 1.f / s;
    }
  // col stats
#pragma unroll
  for (int nt = 0; nt < 8; ++nt) {
    float m = -1e30f;
#pragma unroll
    for (int mt = 0; mt < 2; ++mt)
#pragma unroll
      for (int v = 0; v < 4; ++v) m = fmaxf(m, acc[mt][nt][v]);
    m = fmaxf(m, __shfl_xor(m, 16, 64));
    m = fmaxf(m, __shfl_xor(m, 32, 64));
    if (lg == 0) s_red4[(nt * 16 + lr) * 4 + w] = m;
  }
  __syncthreads();
  if (t < 128) s_cm[t] = fmaxf(fmaxf(s_red4[t * 4], s_red4[t * 4 + 1]),
                               fmaxf(s_red4[t * 4 + 2], s_red4[t * 4 + 3]));
  __syncthreads();
#pragma unroll
  for (int nt = 0; nt < 8; ++nt) {
    const float mc = s_cm[nt * 16 + lr];
    float s = 0.f;
#pragma unroll
    for (int mt = 0; mt < 2; ++mt)
#pragma unroll
      for (int v = 0; v < 4; ++v) s += expf(acc[mt][nt][v] - mc);
    s += __shfl_xor(s, 16, 64);
    s += __shfl_xor(s, 32, 64);
    if (lg == 0) s_red4[(nt * 16 + lr) * 4 + w] = s;
  }
  __syncthreads();
  if (t < 128) s_cd[t] = 1.f / (s_red4[t * 4] + s_red4[t * 4 + 1] +
                                s_red4[t * 4 + 2] + s_red4[t * 4 + 3]);
  __syncthreads();

  f16* SfRow = Srow + (size_t)(b * 18 + tt) * 16384;
  f16* SfT   = ST   + (size_t)(b * 18 + tt) * 16384;
  f16* SbT   = ST   + (size_t)(b * 18 + 17 - tt) * 16384;
  f16* SbRow = Srow + (size_t)(b * 18 + 17 - tt) * 16384;

  float contrib = 0.f;
  // pass 1: Sf row + Sb T direct; stage Sf^T in sT; At_1 loss terms at tt==0
#pragma unroll
  for (int mt = 0; mt < 2; ++mt)
#pragma unroll
    for (int v = 0; v < 4; ++v) {
      const int r = w * 32 + mt * 16 + lg * 4 + v;
      float qsum = 0.f, dval = 0.f;
#pragma unroll
      for (int nt = 0; nt < 8; ++nt) {
        const int c = nt * 16 + lr;
        const float a = acc[mt][nt][v];
        const float sf = expf(a - rm[mt][v]) * rd[mt][v];
        const float sb = expf(a - s_cm[c]) * s_cd[c];
        SfRow[r * 128 + c] = (f16)sf;
        SbT[r * 128 + c] = (f16)sb;
        sT[c * 136 + r] = (f16)sf;
        if (tt == 0) {
          qsum += expf(sb);
          if (nt == (w * 2 + mt)) dval = sb;
        }
      }
      if (tt == 0) {
        qsum += __shfl_xor(qsum, 1, 64);
        qsum += __shfl_xor(qsum, 2, 64);
        qsum += __shfl_xor(qsum, 4, 64);
        qsum += __shfl_xor(qsum, 8, 64);
        if (lr == lg * 4 + v) contrib += dval - logf(qsum);
      }
    }
  __syncthreads();
  if (tt >= 1) {
#pragma unroll
    for (int j = 0; j < 8; ++j) {
      const int e = (j * 256 + t) * 8;
      *(f16x8*)(SfT + e) = *(const f16x8*)&sT[(e >> 7) * 136 + (e & 127)];
    }
  }
  __syncthreads();
  // pass 2: stage Sb row-form (= transpose of col-softmax values)
#pragma unroll
  for (int mt = 0; mt < 2; ++mt)
#pragma unroll
    for (int v = 0; v < 4; ++v) {
      const int r = w * 32 + mt * 16 + lg * 4 + v;
#pragma unroll
      for (int nt = 0; nt < 8; ++nt) {
        const int c = nt * 16 + lr;
        const float sb = expf(acc[mt][nt][v] - s_cm[c]) * s_cd[c];
        sT[c * 136 + r] = (f16)sb;
      }
    }
  __syncthreads();
#pragma unroll
  for (int j = 0; j < 8; ++j) {
    const int e = (j * 256 + t) * 8;
    *(f16x8*)(SbRow + e) = *(const f16x8*)&sT[(e >> 7) * 136 + (e & 127)];
  }
  if (tt == 0) {
#pragma unroll
    for (int off = 1; off < 64; off <<= 1) contrib += __shfl_xor(contrib, off, 64);
    if (lane == 0) s_lred[w] = contrib;
    __syncthreads();
    if (t == 0) atomicAdd(loss, s_lred[0] + s_lred[1] + s_lred[2] + s_lred[3]);
  }
}

// ---- Hillis-Steele matrix scan step (order-preserving products)
// dir0: P_i = M_1..M_i with M_i = S(18-i), i=1..8 (A_i^d = A_{i-s} * A_i)
// dir1: G_i = S_i..S_1, i=1..7                    (B_i^d = B_i * B_{i-s})
__global__ __launch_bounds__(256) void k_scan(
    const int step,
    const f16* __restrict__ Srow, const f16* __restrict__ ST,
    f16* __restrict__ scanR, f16* __restrict__ scanT)
{
  __shared__ __align__(16) f16 sL[16384];
  __shared__ __align__(16) f16 sRt[16384];
  const int bid = blockIdx.x;
  const int dir = bid >> 6, b = bid & 7, i = ((bid >> 3) & 7) + 1;
  if (dir == 1 && i == 8) return;
  const int s = 1 << step;
  const int inpp = (step == 2) ? 1 : 0;      // step0: S arrays; step1: pp0; step2: pp1
  const int outpp = (step == 1) ? 1 : 0;     // step0 -> pp0; step1 -> pp1; step2 -> pp0
  const int t = threadIdx.x, lane = t & 63, w = t >> 6;
  const int lr = lane & 15, lg = lane >> 4;

#define SLOT_R(pp, d, ii) (scanR + ((((size_t)(pp) * 2 + (d)) * 9 + (ii)) * 8 + b) * 16384)
#define SLOT_T(pp, d, ii) (scanT + ((((size_t)(pp) * 2 + (d)) * 9 + (ii)) * 8 + b) * 16384)

  f16* outR = SLOT_R(outpp, dir, i);
  f16* outT = SLOT_T(outpp, dir, i);

  if (i <= s) {  // copy both forms forward
    const f16 *srcR, *srcT;
    if (step == 0) {
      const int j = (dir == 0) ? (18 - i) : i;
      srcR = Srow + (size_t)(b * 18 + j) * 16384;
      srcT = ST + (size_t)(b * 18 + j) * 16384;
    } else {
      srcR = SLOT_R(inpp, dir, i);
      srcT = SLOT_T(inpp, dir, i);
    }
    for (int j = t; j < 2048; j += 256) {
      *(f16x8*)(outR + j * 8) = *(const f16x8*)(srcR + j * 8);
      *(f16x8*)(outT + j * 8) = *(const f16x8*)(srcT + j * 8);
    }
    return;
  }
  const f16 *L, *Rt;
  if (step == 0) {
    if (dir == 0) { L = Srow + (size_t)(b * 18 + (19 - i)) * 16384;
                    Rt = ST + (size_t)(b * 18 + (18 - i)) * 16384; }
    else          { L = Srow + (size_t)(b * 18 + i) * 16384;
                    Rt = ST + (size_t)(b * 18 + (i - 1)) * 16384; }
  } else {
    if (dir == 0) { L = SLOT_R(inpp, 0, i - s); Rt = SLOT_T(inpp, 0, i); }
    else          { L = SLOT_R(inpp, 1, i);     Rt = SLOT_T(inpp, 1, i - s); }
  }
  stage_pair(L, Rt, sL, sRt, t);
  __syncthreads();
  f32x4 acc[2][8] = {};
  mm128(sL, sRt, acc, w, lr, lg);
  // write row form
#pragma unroll
  for (int mt = 0; mt < 2; ++mt)
#pragma unroll
    for (int nt = 0; nt < 8; ++nt)
#pragma unroll
      for (int v = 0; v < 4; ++v)
        outR[(w * 32 + mt * 16 + lg * 4 + v) * 128 + nt * 16 + lr] = (f16)acc[mt][nt][v];
  // write T form
#pragma unroll
  for (int mt = 0; mt < 2; ++mt)
#pragma unroll
    for (int nt = 0; nt < 8; ++nt) {
      f16x4 pk;
#pragma unroll
      for (int v = 0; v < 4; ++v) pk[v] = (f16)acc[mt][nt][v];
      *(f16x4*)(outT + (size_t)(nt * 16 + lr) * 128 + w * 32 + mt * 16 + lg * 4) = pk;
    }
#undef SLOT_R
#undef SLOT_T
}

// ---- loss: At_k = P_k * G_{k-1}, fused column log-softmax diag loss (k=2..8, 56 blocks)
__global__ __launch_bounds__(256) void k_loss(
    const f16* __restrict__ scanR, const f16* __restrict__ scanT,
    float* __restrict__ loss)
{
  __shared__ __align__(16) f16 sL[16384];
  __shared__ __align__(16) f16 sRt[16384];
  const int b = blockIdx.x & 7, k = (blockIdx.x >> 3) + 2;
  const int t = threadIdx.x, lane = t & 63, w = t >> 6;
  const int lr = lane & 15, lg = lane >> 4;
  const f16* L = scanR + (((size_t)0 * 9 + k) * 8 + b) * 16384;             // pp0, dir0, i=k
  const f16* Rt = scanT + ((((size_t)0 * 2 + 1) * 9 + (k - 1)) * 8 + b) * 16384;  // pp0, dir1
  stage_pair(L, Rt, sL, sRt, t);
  __syncthreads();
  f32x4 acc[2][8] = {};
  mm128(sL, sRt, acc, w, lr, lg);
  __syncthreads();
  float* redm = (float*)sL;          // [128][4]
  float* redM = redm + 512;          // [128]
  float* reds = redM + 128;          // [128][4]
  float* redL = reds + 512;          // [128]
  float* redW = redL + 128;          // [4]
#pragma unroll
  for (int nt = 0; nt < 8; ++nt) {
    float pm = -1e30f;
#pragma unroll
    for (int mt = 0; mt < 2; ++mt)
#pragma unroll
      for (int v = 0; v < 4; ++v) pm = fmaxf(pm, acc[mt][nt][v]);
    pm = fmaxf(pm, __shfl_xor(pm, 16, 64));
    pm = fmaxf(pm, __shfl_xor(pm, 32, 64));
    if (lg == 0) redm[(nt * 16 + lr) * 4 + w] = pm;
  }
  __syncthreads();
  if (t < 128) redM[t] = fmaxf(fmaxf(redm[t * 4], redm[t * 4 + 1]),
                               fmaxf(redm[t * 4 + 2], redm[t * 4 + 3]));
  __syncthreads();
#pragma unroll
  for (int nt = 0; nt < 8; ++nt) {
    const float mc = redM[nt * 16 + lr];
    float ps = 0.f;
#pragma unroll
    for (int mt = 0; mt < 2; ++mt)
#pragma unroll
      for (int v = 0; v < 4; ++v) ps += expf(acc[mt][nt][v] - mc);
    ps += __shfl_xor(ps, 16, 64);
    ps += __shfl_xor(ps, 32, 64);
    if (lg == 0) reds[(nt * 16 + lr) * 4 + w] = ps;
  }
  __syncthreads();
  if (t < 128) redL[t] = logf(reds[t * 4] + reds[t * 4 + 1] +
                              reds[t * 4 + 2] + reds[t * 4 + 3]);
  __syncthreads();
  float contrib = 0.f;
#pragma unroll
  for (int mt = 0; mt < 2; ++mt)
#pragma unroll
    for (int nt = 0; nt < 8; ++nt)
#pragma unroll
      for (int v = 0; v < 4; ++v) {
        const int r = w * 32 + mt * 16 + lg * 4 + v, c = nt * 16 + lr;
        if (r == c) contrib += acc[mt][nt][v] - redM[c] - redL[c];
      }
#pragma unroll
  for (int off = 1; off < 64; off <<= 1) contrib += __shfl_xor(contrib, off, 64);
  if (lane == 0) redW[w] = contrib;
  __syncthreads();
  if (t == 0) atomicAdd(loss, redW[0] + redW[1] + redW[2] + redW[3]);
}

__global__ void k_final(const float* __restrict__ acc, float* __restrict__ out) {
  out[0] = -acc[0] * (1.f / 131072.f);
}

extern "C" void kernel_launch(void* const* d_in, const int* in_sizes, int n_in,
                              void* d_out, int out_size, void* d_ws, size_t ws_size,
                              hipStream_t stream) {
  const float* seq = (const float*)d_in[0];
  const float* w1  = (const float*)d_in[1];
  const float* b1  = (const float*)d_in[2];
  const float* w2  = (const float*)d_in[3];
  const float* b2  = (const float*)d_in[4];
  const float* lw  = (const float*)d_in[5];
  const float* lb  = (const float*)d_in[6];
  float* out = (float*)d_out;

  f16* emb16 = (f16*)d_ws;                 // 1,310,720
  f16* Srow  = emb16 + 1310720;            // 2,359,296
  f16* ST    = Srow + 2359296;             // 2,359,296
  f16* scanR = ST + 2359296;               // 2*2*9*8*16384 = 4,718,592
  f16* scanT = scanR + 4718592;            // 4,718,592
  f16* w2p   = scanT + 4718592;            // 36,864
  f16* w1p   = w2p + 36864;                // 1,024
  float* lwT = (float*)(w1p + 1024);       // 8,192 f32
  float* lossAcc = lwT + 8192;             // 1 f32

  float* Aout = out + 1;

  k_repack<<<72, 256, 0, stream>>>(w2, w1, lw, w2p, w1p, lwT, lossAcc);
  k_encoder<<<10240, 256, 0, stream>>>(seq, w1p, b1, w2p, b2, lwT, lb, emb16);
  k_affsm<<<72, 256, 0, stream>>>(emb16, Aout, Srow, ST, lossAcc);
  k_scan<<<128, 256, 0, stream>>>(0, Srow, ST, scanR, scanT);
  k_scan<<<128, 256, 0, stream>>>(1, Srow, ST, scanR, scanT);
  k_scan<<<128, 256, 0, stream>>>(2, Srow, ST, scanR, scanT);
  k_loss<<<56, 256, 0, stream>>>(scanR, scanT, lossAcc);
  k_final<<<1, 1, 0, stream>>>(lossAcc, out);
}

// Round 8
// 238.358 us; speedup vs baseline: 1.7596x; 1.7596x over previous
//
#include <hip/hip_runtime.h>
#include <math.h>

typedef _Float16 f16;
typedef f16 f16x2 __attribute__((ext_vector_type(2)));
typedef f16 f16x4 __attribute__((ext_vector_type(4)));
typedef f16 f16x8 __attribute__((ext_vector_type(8)));
typedef float f32x4 __attribute__((ext_vector_type(4)));

// ---- shared MFMA helpers: 128x128x128 f16 matmul from XOR-swizzled LDS ----
__device__ __forceinline__ void stage_pair(const f16* __restrict__ L,
                                           const f16* __restrict__ Rt,
                                           f16* sL, f16* sRt, int t) {
#pragma unroll
  for (int j = 0; j < 8; ++j) {
    const int ck = j * 256 + t, row = ck >> 4, c16 = ck & 15;
    const int off = ((row << 8) + (c16 << 4)) ^ ((row & 7) << 4);
    *(f16x8*)((char*)sL + off) = *(const f16x8*)(L + ck * 8);
    *(f16x8*)((char*)sRt + off) = *(const f16x8*)(Rt + ck * 8);
  }
}

__device__ __forceinline__ void mm128(const f16* sL, const f16* sRt,
                                      f32x4 acc[2][8], int w, int lr, int lg) {
#pragma unroll
  for (int kt = 0; kt < 4; ++kt) {
    int row = w * 32 + lr;
    int byt = ((row << 8) + kt * 64 + (lg << 4)) ^ ((row & 7) << 4);
    const f16x8 a0 = *(const f16x8*)((const char*)sL + byt);
    row += 16;
    byt = ((row << 8) + kt * 64 + (lg << 4)) ^ ((row & 7) << 4);
    const f16x8 a1 = *(const f16x8*)((const char*)sL + byt);
#pragma unroll
    for (int nt = 0; nt < 8; ++nt) {
      const int rb = nt * 16 + lr;
      const int bb = ((rb << 8) + kt * 64 + (lg << 4)) ^ ((rb & 7) << 4);
      const f16x8 bv = *(const f16x8*)((const char*)sRt + bb);
      acc[0][nt] = __builtin_amdgcn_mfma_f32_16x16x32_f16(a0, bv, acc[0][nt], 0, 0, 0);
      acc[1][nt] = __builtin_amdgcn_mfma_f32_16x16x32_f16(a1, bv, acc[1][nt], 0, 0, 0);
    }
  }
}

// ---- repack: w2 -> f16 hi/lo [h/l][tap][oc][ic]; w1 -> w1p[oc][k32]; lw -> lwT
__global__ __launch_bounds__(256) void k_repack(const float* __restrict__ w2,
                                                const float* __restrict__ w1,
                                                const float* __restrict__ lw,
                                                f16* __restrict__ w2p,
                                                f16* __restrict__ w1p,
                                                float* __restrict__ lwT,
                                                float* __restrict__ lossAcc) {
  const int i = blockIdx.x * 256 + threadIdx.x;
  if (i == 0) lossAcc[0] = 0.f;
  if (i < 18432) {
    const int ic = i & 31, oc = (i >> 5) & 63, tap = i >> 11;
    const float w = w2[oc * 288 + ic * 9 + tap];
    const f16 wh = (f16)w;
    w2p[i] = wh;
    w2p[18432 + i] = (f16)(w - (float)wh);
  }
  if (i < 1024) {
    const int oc = i >> 5, k = i & 31;
    f16 r = (f16)0.f;
    if (k < 9) r = (f16)w1[oc * 9 + k];
    else if (k >= 16 && k < 25) {
      const float w = w1[oc * 9 + (k - 16)];
      r = (f16)(w - (float)((f16)w));
    }
    w1p[i] = r;
  }
  if (i < 8192) lwT[i] = lw[(i & 63) * 128 + (i >> 6)];  // lwT[o][c]
}

// ---- fused encoder (LDS 23.4KB; bounds (256,4) — (256,6) spilled, r7: 637MB scratch writes)
__global__ __launch_bounds__(256, 4) void k_encoder(
    const float* __restrict__ seq,
    const f16* __restrict__ w1p, const float* __restrict__ b1,
    const f16* __restrict__ w2p, const float* __restrict__ b2,
    const float* __restrict__ lwT, const float* __restrict__ lb,
    f16* __restrict__ emb16)
{
  __shared__ __align__(16) f16 s_in16[33 * 34];   // [iy][ix] stride 34
  __shared__ __align__(16) f16 s_h1[289 * 36];    // row = iy*17+ix, stride 36 f16
  __shared__ __align__(16) float s_pool[64];
  __shared__ float s_part[2];
  const int t = threadIdx.x, lane = t & 63, wv = t >> 6;
  const int lr = lane & 15, lg = lane >> 4;

  // stage input as f16 (float4 load, two f16x2 stores)
  {
    const float* x = seq + (size_t)blockIdx.x * 1024;
    const f32x4 v4 = *(const f32x4*)(x + t * 4);
    const int row = t >> 3, col = (t & 7) * 4;
    *(f16x2*)&s_in16[row * 34 + col] = f16x2{(f16)v4[0], (f16)v4[1]};
    *(f16x2*)&s_in16[row * 34 + col + 2] = f16x2{(f16)v4[2], (f16)v4[3]};
  }
  if (t < 32) { s_in16[t * 34 + 32] = (f16)0.f; s_in16[t * 34 + 33] = (f16)0.f; }
  if (t < 34) s_in16[32 * 34 + t] = (f16)0.f;
  // zero h1 pad rows (ix==16: rows 16+17*zi; iy==16: rows 272..288): 33 rows x 32 f16
  for (int zi = t; zi < 264; zi += 256) {
    const int rr = zi >> 3, ch = zi & 7;
    const int row = (rr < 16) ? rr * 17 + 16 : 272 + (rr - 16);
    *(f16x4*)&s_h1[row * 36 + ch * 4] = f16x4{(f16)0.f, (f16)0.f, (f16)0.f, (f16)0.f};
  }
  // conv1 B fragments + biases
  f16x8 w1f[2];
  float b1v[2];
#pragma unroll
  for (int n = 0; n < 2; ++n) {
    w1f[n] = *(const f16x8*)(w1p + (n * 16 + lr) * 32 + lg * 8);
    b1v[n] = b1[n * 16 + lr];
  }
  __syncthreads();

  // conv1 via MFMA: m-tile = output row oy, M=16 ox, N=2x16 oc, K=32 (hi|lo taps)
  {
    const bool odd = lg & 1;
    f32x4 a1[4][2];
#pragma unroll
    for (int m = 0; m < 4; ++m) {
      const int oy = wv * 4 + m;
      const int base = 68 * oy + 2 * lr;
      f16x8 af;
      if (odd) {
        af = f16x8{s_in16[base + 70], (f16)0.f, (f16)0.f, (f16)0.f,
                   (f16)0.f, (f16)0.f, (f16)0.f, (f16)0.f};
      } else {
        af[0] = s_in16[base];      af[1] = s_in16[base + 1];  af[2] = s_in16[base + 2];
        af[3] = s_in16[base + 34]; af[4] = s_in16[base + 35]; af[5] = s_in16[base + 36];
        af[6] = s_in16[base + 68]; af[7] = s_in16[base + 69];
      }
#pragma unroll
      for (int n = 0; n < 2; ++n) {
        const f32x4 c0 = f32x4{b1v[n], b1v[n], b1v[n], b1v[n]};
        a1[m][n] = __builtin_amdgcn_mfma_f32_16x16x32_f16(af, w1f[n], c0, 0, 0, 0);
      }
    }
#pragma unroll
    for (int m = 0; m < 4; ++m) {
      const int oy = wv * 4 + m;
#pragma unroll
      for (int n = 0; n < 2; ++n)
#pragma unroll
        for (int v = 0; v < 4; ++v)
          s_h1[(oy * 17 + lg * 4 + v) * 36 + n * 16 + lr] = (f16)fmaxf(a1[m][n][v], 0.f);
    }
  }
  // conv2 B-fragments (hi/lo)
  f16x8 bh[9], bl[9];
  float bias2;
  {
    const int oc = wv * 16 + lr;
#pragma unroll
    for (int tap = 0; tap < 9; ++tap) {
      bh[tap] = *(const f16x8*)(w2p + ((tap * 64 + oc) * 32 + lg * 8));
      bl[tap] = *(const f16x8*)(w2p + 18432 + ((tap * 64 + oc) * 32 + lg * 8));
    }
    bias2 = b2[oc];
  }
  __syncthreads();

  // conv2 MFMA: M=64 pos (4 tiles), N=16 oc (this wave), K=32 ic per tap
  {
    f32x4 acc[4];
#pragma unroll
    for (int m = 0; m < 4; ++m) acc[m] = f32x4{bias2, bias2, bias2, bias2};
#pragma unroll
    for (int m = 0; m < 4; ++m) {
      const int opos = m * 16 + lr, oy = opos >> 3, ox = opos & 7;
      const int baddr = (34 * oy + 2 * ox) * 36 + lg * 8;
#pragma unroll
      for (int dy = 0; dy < 3; ++dy)
#pragma unroll
        for (int dx = 0; dx < 3; ++dx) {
          const int tap = dy * 3 + dx;
          const f16x8 afr = *(const f16x8*)&s_h1[baddr + (dy * 17 + dx) * 36];
          acc[m] = __builtin_amdgcn_mfma_f32_16x16x32_f16(afr, bh[tap], acc[m], 0, 0, 0);
          acc[m] = __builtin_amdgcn_mfma_f32_16x16x32_f16(afr, bl[tap], acc[m], 0, 0, 0);
        }
    }
    float s = 0.f;
#pragma unroll
    for (int m = 0; m < 4; ++m)
#pragma unroll
      for (int v = 0; v < 4; ++v) s += fmaxf(acc[m][v], 0.f);
    s += __shfl_xor(s, 16, 64);
    s += __shfl_xor(s, 32, 64);
    if (lane < 16) s_pool[wv * 16 + lane] = s * (1.f / 64.f);
  }
  __syncthreads();
  // linear 64->128 + L2 normalize, f16 out
  float val = 0.f;
  if (t < 128) {
    val = lb[t];
    const float* lrow = lwT + t * 64;
#pragma unroll
    for (int c4 = 0; c4 < 16; ++c4) {
      const f32x4 wv4 = *(const f32x4*)(lrow + c4 * 4);
      const f32x4 pv = *(const f32x4*)&s_pool[c4 * 4];
      val = fmaf(pv[0], wv4[0], val);
      val = fmaf(pv[1], wv4[1], val);
      val = fmaf(pv[2], wv4[2], val);
      val = fmaf(pv[3], wv4[3], val);
    }
  }
  float sq = val * val;
#pragma unroll
  for (int off = 1; off < 64; off <<= 1) sq += __shfl_xor(sq, off, 64);
  if (t < 128 && (t & 63) == 0) s_part[t >> 6] = sq;
  __syncthreads();
  if (t < 128) {
    const float nrm = sqrtf(s_part[0] + s_part[1]);
    emb16[(size_t)blockIdx.x * 128 + t] = (f16)(val / fmaxf(nrm, 1e-12f));
  }
}

// ---- fused affinity + dual softmax; stores row+T forms of both S matrices; At_1 loss at tt==0
__global__ __launch_bounds__(256) void k_affsm(
    const f16* __restrict__ emb16, float* __restrict__ Aout,
    f16* __restrict__ Srow, f16* __restrict__ ST, float* __restrict__ loss)
{
  __shared__ __align__(16) f16 sL[16384];
  __shared__ __align__(16) f16 sR[16384];
  __shared__ __align__(16) f16 sT[128 * 136];
  __shared__ float s_cm[128], s_cd[128];
  __shared__ float s_red4[512];
  __shared__ float s_lred[4];
  const int bid = blockIdx.x, b = bid / 9, tt = bid % 9;
  const int t = threadIdx.x, lane = t & 63, w = t >> 6;
  const int lr = lane & 15, lg = lane >> 4;
  const f16* Ea = emb16 + (size_t)(b * 10 + tt) * 16384;
  stage_pair(Ea, Ea + 16384, sL, sR, t);
  __syncthreads();
  f32x4 acc[2][8] = {};
  mm128(sL, sR, acc, w, lr, lg);
#pragma unroll
  for (int mt = 0; mt < 2; ++mt)
#pragma unroll
    for (int nt = 0; nt < 8; ++nt)
#pragma unroll
      for (int v = 0; v < 4; ++v) acc[mt][nt][v] *= (1.f / 0.07f);

  // write A
  float* Og = Aout + (size_t)bid * 16384;
#pragma unroll
  for (int mt = 0; mt < 2; ++mt)
#pragma unroll
    for (int nt = 0; nt < 8; ++nt)
#pragma unroll
      for (int v = 0; v < 4; ++v)
        Og[(w * 32 + mt * 16 + lg * 4 + v) * 128 + nt * 16 + lr] = acc[mt][nt][v];

  if (tt == 8) return;

  // row stats
  float rm[2][4], rd[2][4];
#pragma unroll
  for (int mt = 0; mt < 2; ++mt)
#pragma unroll
    for (int v = 0; v < 4; ++v) {
      float m = -1e30f;
#pragma unroll
      for (int nt = 0; nt < 8; ++nt) m = fmaxf(m, acc[mt][nt][v]);
      m = fmaxf(m, __shfl_xor(m, 1, 64));
      m = fmaxf(m, __shfl_xor(m, 2, 64));
      m = fmaxf(m, __shfl_xor(m, 4, 64));
      m = fmaxf(m, __shfl_xor(m, 8, 64));
      float s = 0.f;
#pragma unroll
      for (int nt = 0; nt < 8; ++nt) s += expf(acc[mt][nt][v] - m);
      s += __shfl_xor(s, 1, 64);
      s += __shfl_xor(s, 2, 64);
      s += __shfl_xor(s, 4, 64);
      s += __shfl_xor(s, 8, 64);
      rm[mt][v] = m;
      rd[mt][v] = 1.f / s;
    }
  // col stats
#pragma unroll
  for (int nt = 0; nt < 8; ++nt) {
    float m = -1e30f;
#pragma unroll
    for (int mt = 0; mt < 2; ++mt)
#pragma unroll
      for (int v = 0; v < 4; ++v) m = fmaxf(m, acc[mt][nt][v]);
    m = fmaxf(m, __shfl_xor(m, 16, 64));
    m = fmaxf(m, __shfl_xor(m, 32, 64));
    if (lg == 0) s_red4[(nt * 16 + lr) * 4 + w] = m;
  }
  __syncthreads();
  if (t < 128) s_cm[t] = fmaxf(fmaxf(s_red4[t * 4], s_red4[t * 4 + 1]),
                               fmaxf(s_red4[t * 4 + 2], s_red4[t * 4 + 3]));
  __syncthreads();
#pragma unroll
  for (int nt = 0; nt < 8; ++nt) {
    const float mc = s_cm[nt * 16 + lr];
    float s = 0.f;
#pragma unroll
    for (int mt = 0; mt < 2; ++mt)
#pragma unroll
      for (int v = 0; v < 4; ++v) s += expf(acc[mt][nt][v] - mc);
    s += __shfl_xor(s, 16, 64);
    s += __shfl_xor(s, 32, 64);
    if (lg == 0) s_red4[(nt * 16 + lr) * 4 + w] = s;
  }
  __syncthreads();
  if (t < 128) s_cd[t] = 1.f / (s_red4[t * 4] + s_red4[t * 4 + 1] +
                                s_red4[t * 4 + 2] + s_red4[t * 4 + 3]);
  __syncthreads();

  f16* SfRow = Srow + (size_t)(b * 18 + tt) * 16384;
  f16* SfT   = ST   + (size_t)(b * 18 + tt) * 16384;
  f16* SbT   = ST   + (size_t)(b * 18 + 17 - tt) * 16384;
  f16* SbRow = Srow + (size_t)(b * 18 + 17 - tt) * 16384;

  float contrib = 0.f;
  // pass 1: Sf row + Sb T direct; stage Sf^T in sT; At_1 loss terms at tt==0
#pragma unroll
  for (int mt = 0; mt < 2; ++mt)
#pragma unroll
    for (int v = 0; v < 4; ++v) {
      const int r = w * 32 + mt * 16 + lg * 4 + v;
      float qsum = 0.f, dval = 0.f;
#pragma unroll
      for (int nt = 0; nt < 8; ++nt) {
        const int c = nt * 16 + lr;
        const float a = acc[mt][nt][v];
        const float sf = expf(a - rm[mt][v]) * rd[mt][v];
        const float sb = expf(a - s_cm[c]) * s_cd[c];
        SfRow[r * 128 + c] = (f16)sf;
        SbT[r * 128 + c] = (f16)sb;
        sT[c * 136 + r] = (f16)sf;
        if (tt == 0) {
          qsum += expf(sb);
          if (nt == (w * 2 + mt)) dval = sb;
        }
      }
      if (tt == 0) {
        qsum += __shfl_xor(qsum, 1, 64);
        qsum += __shfl_xor(qsum, 2, 64);
        qsum += __shfl_xor(qsum, 4, 64);
        qsum += __shfl_xor(qsum, 8, 64);
        if (lr == lg * 4 + v) contrib += dval - logf(qsum);
      }
    }
  __syncthreads();
  if (tt >= 1) {
#pragma unroll
    for (int j = 0; j < 8; ++j) {
      const int e = (j * 256 + t) * 8;
      *(f16x8*)(SfT + e) = *(const f16x8*)&sT[(e >> 7) * 136 + (e & 127)];
    }
  }
  __syncthreads();
  // pass 2: stage Sb row-form (= transpose of col-softmax values)
#pragma unroll
  for (int mt = 0; mt < 2; ++mt)
#pragma unroll
    for (int v = 0; v < 4; ++v) {
      const int r = w * 32 + mt * 16 + lg * 4 + v;
#pragma unroll
      for (int nt = 0; nt < 8; ++nt) {
        const int c = nt * 16 + lr;
        const float sb = expf(acc[mt][nt][v] - s_cm[c]) * s_cd[c];
        sT[c * 136 + r] = (f16)sb;
      }
    }
  __syncthreads();
#pragma unroll
  for (int j = 0; j < 8; ++j) {
    const int e = (j * 256 + t) * 8;
    *(f16x8*)(SbRow + e) = *(const f16x8*)&sT[(e >> 7) * 136 + (e & 127)];
  }
  if (tt == 0) {
#pragma unroll
    for (int off = 1; off < 64; off <<= 1) contrib += __shfl_xor(contrib, off, 64);
    if (lane == 0) s_lred[w] = contrib;
    __syncthreads();
    if (t == 0) atomicAdd(loss, s_lred[0] + s_lred[1] + s_lred[2] + s_lred[3]);
  }
}

// ---- Hillis-Steele matrix scan step (order-preserving products)
// dir0: P_i = M_1..M_i with M_i = S(18-i), i=1..8 (A_i^d = A_{i-s} * A_i)
// dir1: G_i = S_i..S_1, i=1..7                    (B_i^d = B_i * B_{i-s})
__global__ __launch_bounds__(256) void k_scan(
    const int step,
    const f16* __restrict__ Srow, const f16* __restrict__ ST,
    f16* __restrict__ scanR, f16* __restrict__ scanT)
{
  __shared__ __align__(16) f16 sL[16384];
  __shared__ __align__(16) f16 sRt[16384];
  const int bid = blockIdx.x;
  const int dir = bid >> 6, b = bid & 7, i = ((bid >> 3) & 7) + 1;
  if (dir == 1 && i == 8) return;
  const int s = 1 << step;
  const int inpp = (step == 2) ? 1 : 0;      // step0: S arrays; step1: pp0; step2: pp1
  const int outpp = (step == 1) ? 1 : 0;     // step0 -> pp0; step1 -> pp1; step2 -> pp0
  const int t = threadIdx.x, lane = t & 63, w = t >> 6;
  const int lr = lane & 15, lg = lane >> 4;

#define SLOT_R(pp, d, ii) (scanR + ((((size_t)(pp) * 2 + (d)) * 9 + (ii)) * 8 + b) * 16384)
#define SLOT_T(pp, d, ii) (scanT + ((((size_t)(pp) * 2 + (d)) * 9 + (ii)) * 8 + b) * 16384)

  f16* outR = SLOT_R(outpp, dir, i);
  f16* outT = SLOT_T(outpp, dir, i);

  if (i <= s) {  // copy both forms forward
    const f16 *srcR, *srcT;
    if (step == 0) {
      const int j = (dir == 0) ? (18 - i) : i;
      srcR = Srow + (size_t)(b * 18 + j) * 16384;
      srcT = ST + (size_t)(b * 18 + j) * 16384;
    } else {
      srcR = SLOT_R(inpp, dir, i);
      srcT = SLOT_T(inpp, dir, i);
    }
    for (int j = t; j < 2048; j += 256) {
      *(f16x8*)(outR + j * 8) = *(const f16x8*)(srcR + j * 8);
      *(f16x8*)(outT + j * 8) = *(const f16x8*)(srcT + j * 8);
    }
    return;
  }
  const f16 *L, *Rt;
  if (step == 0) {
    if (dir == 0) { L = Srow + (size_t)(b * 18 + (19 - i)) * 16384;
                    Rt = ST + (size_t)(b * 18 + (18 - i)) * 16384; }
    else          { L = Srow + (size_t)(b * 18 + i) * 16384;
                    Rt = ST + (size_t)(b * 18 + (i - 1)) * 16384; }
  } else {
    if (dir == 0) { L = SLOT_R(inpp, 0, i - s); Rt = SLOT_T(inpp, 0, i); }
    else          { L = SLOT_R(inpp, 1, i);     Rt = SLOT_T(inpp, 1, i - s); }
  }
  stage_pair(L, Rt, sL, sRt, t);
  __syncthreads();
  f32x4 acc[2][8] = {};
  mm128(sL, sRt, acc, w, lr, lg);
  // write row form
#pragma unroll
  for (int mt = 0; mt < 2; ++mt)
#pragma unroll
    for (int nt = 0; nt < 8; ++nt)
#pragma unroll
      for (int v = 0; v < 4; ++v)
        outR[(w * 32 + mt * 16 + lg * 4 + v) * 128 + nt * 16 + lr] = (f16)acc[mt][nt][v];
  // write T form
#pragma unroll
  for (int mt = 0; mt < 2; ++mt)
#pragma unroll
    for (int nt = 0; nt < 8; ++nt) {
      f16x4 pk;
#pragma unroll
      for (int v = 0; v < 4; ++v) pk[v] = (f16)acc[mt][nt][v];
      *(f16x4*)(outT + (size_t)(nt * 16 + lr) * 128 + w * 32 + mt * 16 + lg * 4) = pk;
    }
#undef SLOT_R
#undef SLOT_T
}

// ---- loss: At_k = P_k * G_{k-1}, fused column log-softmax diag loss (k=2..8, 56 blocks)
__global__ __launch_bounds__(256) void k_loss(
    const f16* __restrict__ scanR, const f16* __restrict__ scanT,
    float* __restrict__ loss)
{
  __shared__ __align__(16) f16 sL[16384];
  __shared__ __align__(16) f16 sRt[16384];
  const int b = blockIdx.x & 7, k = (blockIdx.x >> 3) + 2;
  const int t = threadIdx.x, lane = t & 63, w = t >> 6;
  const int lr = lane & 15, lg = lane >> 4;
  const f16* L = scanR + (((size_t)0 * 9 + k) * 8 + b) * 16384;             // pp0, dir0, i=k
  const f16* Rt = scanT + ((((size_t)0 * 2 + 1) * 9 + (k - 1)) * 8 + b) * 16384;  // pp0, dir1
  stage_pair(L, Rt, sL, sRt, t);
  __syncthreads();
  f32x4 acc[2][8] = {};
  mm128(sL, sRt, acc, w, lr, lg);
  __syncthreads();
  float* redm = (float*)sL;          // [128][4]
  float* redM = redm + 512;          // [128]
  float* reds = redM + 128;          // [128][4]
  float* redL = reds + 512;          // [128]
  float* redW = redL + 128;          // [4]
#pragma unroll
  for (int nt = 0; nt < 8; ++nt) {
    float pm = -1e30f;
#pragma unroll
    for (int mt = 0; mt < 2; ++mt)
#pragma unroll
      for (int v = 0; v < 4; ++v) pm = fmaxf(pm, acc[mt][nt][v]);
    pm = fmaxf(pm, __shfl_xor(pm, 16, 64));
    pm = fmaxf(pm, __shfl_xor(pm, 32, 64));
    if (lg == 0) redm[(nt * 16 + lr) * 4 + w] = pm;
  }
  __syncthreads();
  if (t < 128) redM[t] = fmaxf(fmaxf(redm[t * 4], redm[t * 4 + 1]),
                               fmaxf(redm[t * 4 + 2], redm[t * 4 + 3]));
  __syncthreads();
#pragma unroll
  for (int nt = 0; nt < 8; ++nt) {
    const float mc = redM[nt * 16 + lr];
    float ps = 0.f;
#pragma unroll
    for (int mt = 0; mt < 2; ++mt)
#pragma unroll
      for (int v = 0; v < 4; ++v) ps += expf(acc[mt][nt][v] - mc);
    ps += __shfl_xor(ps, 16, 64);
    ps += __shfl_xor(ps, 32, 64);
    if (lg == 0) reds[(nt * 16 + lr) * 4 + w] = ps;
  }
  __syncthreads();
  if (t < 128) redL[t] = logf(reds[t * 4] + reds[t * 4 + 1] +
                              reds[t * 4 + 2] + reds[t * 4 + 3]);
  __syncthreads();
  float contrib = 0.f;
#pragma unroll
  for (int mt = 0; mt < 2; ++mt)
#pragma unroll
    for (int nt = 0; nt < 8; ++nt)
#pragma unroll
      for (int v = 0; v < 4; ++v) {
        const int r = w * 32 + mt * 16 + lg * 4 + v, c = nt * 16 + lr;
        if (r == c) contrib += acc[mt][nt][v] - redM[c] - redL[c];
      }
#pragma unroll
  for (int off = 1; off < 64; off <<= 1) contrib += __shfl_xor(contrib, off, 64);
  if (lane == 0) redW[w] = contrib;
  __syncthreads();
  if (t == 0) atomicAdd(loss, redW[0] + redW[1] + redW[2] + redW[3]);
}

__global__ void k_final(const float* __restrict__ acc, float* __restrict__ out) {
  out[0] = -acc[0] * (1.f / 131072.f);
}

extern "C" void kernel_launch(void* const* d_in, const int* in_sizes, int n_in,
                              void* d_out, int out_size, void* d_ws, size_t ws_size,
                              hipStream_t stream) {
  const float* seq = (const float*)d_in[0];
  const float* w1  = (const float*)d_in[1];
  const float* b1  = (const float*)d_in[2];
  const float* w2  = (const float*)d_in[3];
  const float* b2  = (const float*)d_in[4];
  const float* lw  = (const float*)d_in[5];
  const float* lb  = (const float*)d_in[6];
  float* out = (float*)d_out;

  f16* emb16 = (f16*)d_ws;                 // 1,310,720
  f16* Srow  = emb16 + 1310720;            // 2,359,296
  f16* ST    = Srow + 2359296;             // 2,359,296
  f16* scanR = ST + 2359296;               // 2*2*9*8*16384 = 4,718,592
  f16* scanT = scanR + 4718592;            // 4,718,592
  f16* w2p   = scanT + 4718592;            // 36,864
  f16* w1p   = w2p + 36864;                // 1,024
  float* lwT = (float*)(w1p + 1024);       // 8,192 f32
  float* lossAcc = lwT + 8192;             // 1 f32

  float* Aout = out + 1;

  k_repack<<<72, 256, 0, stream>>>(w2, w1, lw, w2p, w1p, lwT, lossAcc);
  k_encoder<<<10240, 256, 0, stream>>>(seq, w1p, b1, w2p, b2, lwT, lb, emb16);
  k_affsm<<<72, 256, 0, stream>>>(emb16, Aout, Srow, ST, lossAcc);
  k_scan<<<128, 256, 0, stream>>>(0, Srow, ST, scanR, scanT);
  k_scan<<<128, 256, 0, stream>>>(1, Srow, ST, scanR, scanT);
  k_scan<<<128, 256, 0, stream>>>(2, Srow, ST, scanR, scanT);
  k_loss<<<56, 256, 0, stream>>>(scanR, scanT, lossAcc);
  k_final<<<1, 1, 0, stream>>>(lossAcc, out);
}